// Round 1
// baseline (249.389 us; speedup 1.0000x reference)
//
#include <hip/hip_runtime.h>
#include <math.h>

#define NPTS 300000
#define K 64
#define P 32
#define DETC 1e-16f
// ws floats: [0,64) N_k | [64,128) S_k | [128,2176) M[d][k] | [2176] int counter
#define WS_FLOATS (K + K + K * P)

#define NBLOCKS 2048
#define NTHREADS 256
#define NWAVES (NBLOCKS * (NTHREADS / 64))            // 8192
#define CHUNK ((NPTS + NWAVES - 1) / NWAVES)          // 37  (<64: one u-phase per wave)

// ---- DPP helpers: sum across 64 lanes with VALU-only latency ----
#define DPP_ADD(v, ctrl)                                                     \
    v += __int_as_float(__builtin_amdgcn_update_dpp(                         \
        0, __float_as_int(v), (ctrl), 0xF, 0xF, true))

__device__ __forceinline__ float rl(float x, int lane) {
    return __int_as_float(__builtin_amdgcn_readlane(__float_as_int(x), lane));
}

__global__ __launch_bounds__(NTHREADS, 4) void em_pass(
    const float* __restrict__ mu_phi,
    const float* __restrict__ log_cov_phi,
    const float* __restrict__ pi_k,
    const float* __restrict__ mu_k,
    const float* __restrict__ log_cov_k,
    float* __restrict__ gamma_out,
    float* __restrict__ out_tail,   // pi_new | mu_new | log_cov_new
    float* __restrict__ ws)
{
    const int lane = threadIdx.x & 63;                 // = cluster index
    const int wave = threadIdx.x >> 6;
    const int gw = __builtin_amdgcn_readfirstlane(blockIdx.x * (NTHREADS / 64) + wave);

    // ---- per-lane cluster constants (icov folded into mk2) ----
    const float lck  = log_cov_k[lane];
    const float icov = __expf(-lck);
    const float pik  = pi_k[lane];

    float mk2[P];
    float n2k = 0.f;
#pragma unroll
    for (int d = 0; d < P; ++d) {
        const float m = mu_k[lane * P + d];
        mk2[d] = icov * m;
        n2k = fmaf(m, m, n2k);
    }
    // exponent = sum_d row[d]*mk2[d] - 0.5*icov*u + 16*lcp - Ak
    const float Ak     = 0.5f * (32.f * lck - 32.f + icov * n2k) - __logf(pik);
    const float negAk  = -Ak;
    const float nhicov = -0.5f * icov;

    float accN = 0.f, accS = 0.f;
    float accM[P];
#pragma unroll
    for (int d = 0; d < P; ++d) accM[d] = 0.f;

    const int start = gw * CHUNK;
    const int end0  = (start + CHUNK < NPTS) ? (start + CHUNK) : NPTS;
    const int cnt   = end0 - start;

    if (cnt > 0) {
        // ---- u-phase: lane = point. Two rounds of 4x float4 to cap the
        //      register spike at 16 live floats (keeps accM/mk2 in VGPRs) ----
        float u_v = 0.f, bl_v = 0.f;
        if (lane < cnt) {
            const float4* r4 =
                reinterpret_cast<const float4*>(mu_phi + (size_t)(start + lane) * P);
            float n2 = 0.f;
#pragma unroll 1
            for (int q = 0; q < 8; q += 4) {
                float4 a = r4[q], b = r4[q + 1], c = r4[q + 2], e = r4[q + 3];
                n2 = fmaf(a.x, a.x, n2); n2 = fmaf(a.y, a.y, n2);
                n2 = fmaf(a.z, a.z, n2); n2 = fmaf(a.w, a.w, n2);
                n2 = fmaf(b.x, b.x, n2); n2 = fmaf(b.y, b.y, n2);
                n2 = fmaf(b.z, b.z, n2); n2 = fmaf(b.w, b.w, n2);
                n2 = fmaf(c.x, c.x, n2); n2 = fmaf(c.y, c.y, n2);
                n2 = fmaf(c.z, c.z, n2); n2 = fmaf(c.w, c.w, n2);
                n2 = fmaf(e.x, e.x, n2); n2 = fmaf(e.y, e.y, n2);
                n2 = fmaf(e.z, e.z, n2); n2 = fmaf(e.w, e.w, n2);
            }
            const float lcp = log_cov_phi[start + lane];
            u_v  = fmaf(32.f, __expf(lcp), n2);   // P*e^lcp + ||phi||^2
            bl_v = 16.f * lcp;
        }

        // ---- per-point phase: lane = cluster; row via uniform (scalar) loads ----
#pragma unroll 2
        for (int p = 0; p < cnt; ++p) {
            const int i = start + p;
            const float u_s  = rl(u_v, p);
            const float bl_s = rl(bl_v, p);
            const float* row = mu_phi + (size_t)i * P;   // uniform -> s_load

            // 4 independent FMA chains (8 deep each)
            float d0 = 0.f, d1 = 0.f, d2 = 0.f, d3 = 0.f;
#pragma unroll
            for (int d = 0; d < P; d += 4) {
                d0 = fmaf(row[d + 0], mk2[d + 0], d0);
                d1 = fmaf(row[d + 1], mk2[d + 1], d1);
                d2 = fmaf(row[d + 2], mk2[d + 2], d2);
                d3 = fmaf(row[d + 3], mk2[d + 3], d3);
            }
            const float dot = (d0 + d1) + (d2 + d3);

            // arg = dot + (nhicov*u - Ak) + 16*lcp   (each op <=1 SGPR operand)
            const float tpart = fmaf(nhicov, u_s, negAk);
            const float w = __expf((dot + tpart) + bl_s);

            // wave-64 sum via DPP (VALU) + readlane combine
            float v = w;
            DPP_ADD(v, 0xB1);   // quad_perm xor1
            DPP_ADD(v, 0x4E);   // quad_perm xor2
            DPP_ADD(v, 0x128);  // row_ror:8
            DPP_ADD(v, 0x124);  // row_ror:4  -> each lane = its 16-row sum
            const float sum = (rl(v, 0) + rl(v, 16)) + (rl(v, 32) + rl(v, 48));

            const float g = fmaf(w, __builtin_amdgcn_rcpf(sum), DETC);
            __builtin_nontemporal_store(g, gamma_out + (size_t)i * K + lane); // coalesced 256B

            accN += g;
            accS  = fmaf(g, u_s, accS);
#pragma unroll
            for (int d = 0; d < P; ++d) accM[d] = fmaf(g, row[d], accM[d]);
        }
    }

    // ---- block combine in LDS, then one set of global atomics ----
    __shared__ float lN[K], lS[K], lM[K * P];
    for (int idx = threadIdx.x; idx < K; idx += NTHREADS) { lN[idx] = 0.f; lS[idx] = 0.f; }
    for (int idx = threadIdx.x; idx < K * P; idx += NTHREADS) lM[idx] = 0.f;
    __syncthreads();

    atomicAdd(&lN[lane], accN);
    atomicAdd(&lS[lane], accS);
#pragma unroll
    for (int d = 0; d < P; ++d) atomicAdd(&lM[d * K + lane], accM[d]);
    __syncthreads();

    for (int idx = threadIdx.x; idx < K; idx += NTHREADS) {
        atomicAdd(&ws[idx], lN[idx]);
        atomicAdd(&ws[K + idx], lS[idx]);
    }
    for (int idx = threadIdx.x; idx < K * P; idx += NTHREADS)
        atomicAdd(&ws[2 * K + idx], lM[idx]);
    __syncthreads();   // all this block's global atomics drained

    // ---- decoupled finalize: last block computes the small outputs ----
    __shared__ int lastf;
    if (threadIdx.x == 0) {
        __threadfence();
        const int c = atomicAdd((int*)(ws + WS_FLOATS), 1);
        lastf = (c == NBLOCKS - 1);
    }
    __syncthreads();
    if (lastf) {
        __threadfence();
        const int k = threadIdx.x;
        if (k < K) {
            const float Nk = __hip_atomic_load(&ws[k],     __ATOMIC_RELAXED, __HIP_MEMORY_SCOPE_AGENT);
            const float S  = __hip_atomic_load(&ws[K + k], __ATOMIC_RELAXED, __HIP_MEMORY_SCOPE_AGENT);
            float* pi_new      = out_tail;
            float* mu_new      = out_tail + K;
            float* log_cov_new = out_tail + K + K * P;

            pi_new[k] = Nk / (float)NPTS;
            const float invN = 1.f / Nk;
            float m2 = 0.f;
#pragma unroll
            for (int d = 0; d < P; ++d) {
                const float md = __hip_atomic_load(&ws[2 * K + d * K + k],
                                                   __ATOMIC_RELAXED, __HIP_MEMORY_SCOPE_AGENT) * invN;
                mu_new[k * P + d] = md;
                m2 = fmaf(md, md, m2);
            }
            const float cov = (S - Nk * m2) / (32.f * Nk);
            log_cov_new[k] = logf(cov);
        }
    }
}

extern "C" void kernel_launch(void* const* d_in, const int* in_sizes, int n_in,
                              void* d_out, int out_size, void* d_ws, size_t ws_size,
                              hipStream_t stream)
{
    const float* mu_phi      = (const float*)d_in[0];
    const float* log_cov_phi = (const float*)d_in[1];
    const float* pi_k        = (const float*)d_in[2];
    const float* mu_k        = (const float*)d_in[3];
    const float* log_cov_k   = (const float*)d_in[4];
    float* out = (float*)d_out;
    float* ws  = (float*)d_ws;

    hipMemsetAsync(ws, 0, (WS_FLOATS + 1) * sizeof(float), stream);
    em_pass<<<NBLOCKS, NTHREADS, 0, stream>>>(mu_phi, log_cov_phi, pi_k, mu_k,
                                              log_cov_k, out,
                                              out + (size_t)NPTS * K, ws);
}

// Round 2
// 245.666 us; speedup vs baseline: 1.0152x; 1.0152x over previous
//
#include <hip/hip_runtime.h>
#include <math.h>

#define NPTS 300000
#define K 64
#define P 32
#define DETC 1e-16f
// one accumulator copy: [0,64) N_k | [64,128) S_k | [128,2176) M[d][k]
#define WS_FLOATS (K + K + K * P)
// striped copies to avoid same-line atomic serialization across 8 XCDs
#define NCOPIES 32

#define NBLOCKS 2048
#define NTHREADS 256
#define NWAVES (NBLOCKS * (NTHREADS / 64))            // 8192
#define CHUNK ((NPTS + NWAVES - 1) / NWAVES)          // 37  (<64: one u-phase per wave)

// ---- DPP helpers: sum across 64 lanes with VALU-only latency ----
#define DPP_ADD(v, ctrl)                                                     \
    v += __int_as_float(__builtin_amdgcn_update_dpp(                         \
        0, __float_as_int(v), (ctrl), 0xF, 0xF, true))

__device__ __forceinline__ float rl(float x, int lane) {
    return __int_as_float(__builtin_amdgcn_readlane(__float_as_int(x), lane));
}

__global__ __launch_bounds__(NTHREADS, 4) void em_pass(
    const float* __restrict__ mu_phi,
    const float* __restrict__ log_cov_phi,
    const float* __restrict__ pi_k,
    const float* __restrict__ mu_k,
    const float* __restrict__ log_cov_k,
    float* __restrict__ gamma_out,
    float* __restrict__ out_tail,   // pi_new | mu_new | log_cov_new
    float* __restrict__ ws)
{
    const int lane = threadIdx.x & 63;                 // = cluster index
    const int wave = threadIdx.x >> 6;
    const int gw = __builtin_amdgcn_readfirstlane(blockIdx.x * (NTHREADS / 64) + wave);

    // ---- per-lane cluster constants (icov folded into mk2) ----
    const float lck  = log_cov_k[lane];
    const float icov = __expf(-lck);
    const float pik  = pi_k[lane];

    float mk2[P];
    float n2k = 0.f;
#pragma unroll
    for (int d = 0; d < P; ++d) {
        const float m = mu_k[lane * P + d];
        mk2[d] = icov * m;
        n2k = fmaf(m, m, n2k);
    }
    // exponent = sum_d row[d]*mk2[d] - 0.5*icov*u + 16*lcp - Ak
    const float Ak     = 0.5f * (32.f * lck - 32.f + icov * n2k) - __logf(pik);
    const float negAk  = -Ak;
    const float nhicov = -0.5f * icov;

    float accN = 0.f, accS = 0.f;
    float accM[P];
#pragma unroll
    for (int d = 0; d < P; ++d) accM[d] = 0.f;

    const int start = gw * CHUNK;
    const int end0  = (start + CHUNK < NPTS) ? (start + CHUNK) : NPTS;
    const int cnt   = end0 - start;

    if (cnt > 0) {
        // ---- u-phase: lane = point. Two rounds of 4x float4 to cap the
        //      register spike at 16 live floats (keeps accM/mk2 in VGPRs) ----
        float u_v = 0.f, bl_v = 0.f;
        if (lane < cnt) {
            const float4* r4 =
                reinterpret_cast<const float4*>(mu_phi + (size_t)(start + lane) * P);
            float n2 = 0.f;
#pragma unroll 1
            for (int q = 0; q < 8; q += 4) {
                float4 a = r4[q], b = r4[q + 1], c = r4[q + 2], e = r4[q + 3];
                n2 = fmaf(a.x, a.x, n2); n2 = fmaf(a.y, a.y, n2);
                n2 = fmaf(a.z, a.z, n2); n2 = fmaf(a.w, a.w, n2);
                n2 = fmaf(b.x, b.x, n2); n2 = fmaf(b.y, b.y, n2);
                n2 = fmaf(b.z, b.z, n2); n2 = fmaf(b.w, b.w, n2);
                n2 = fmaf(c.x, c.x, n2); n2 = fmaf(c.y, c.y, n2);
                n2 = fmaf(c.z, c.z, n2); n2 = fmaf(c.w, c.w, n2);
                n2 = fmaf(e.x, e.x, n2); n2 = fmaf(e.y, e.y, n2);
                n2 = fmaf(e.z, e.z, n2); n2 = fmaf(e.w, e.w, n2);
            }
            const float lcp = log_cov_phi[start + lane];
            u_v  = fmaf(32.f, __expf(lcp), n2);   // P*e^lcp + ||phi||^2
            bl_v = 16.f * lcp;
        }

        // ---- per-point phase: lane = cluster; row via uniform (scalar) loads ----
#pragma unroll 2
        for (int p = 0; p < cnt; ++p) {
            const int i = start + p;
            const float u_s  = rl(u_v, p);
            const float bl_s = rl(bl_v, p);
            const float* row = mu_phi + (size_t)i * P;   // uniform -> s_load

            // 4 independent FMA chains (8 deep each)
            float d0 = 0.f, d1 = 0.f, d2 = 0.f, d3 = 0.f;
#pragma unroll
            for (int d = 0; d < P; d += 4) {
                d0 = fmaf(row[d + 0], mk2[d + 0], d0);
                d1 = fmaf(row[d + 1], mk2[d + 1], d1);
                d2 = fmaf(row[d + 2], mk2[d + 2], d2);
                d3 = fmaf(row[d + 3], mk2[d + 3], d3);
            }
            const float dot = (d0 + d1) + (d2 + d3);

            // arg = dot + (nhicov*u - Ak) + 16*lcp   (each op <=1 SGPR operand)
            const float tpart = fmaf(nhicov, u_s, negAk);
            const float w = __expf((dot + tpart) + bl_s);

            // wave-64 sum via DPP (VALU) + readlane combine
            float v = w;
            DPP_ADD(v, 0xB1);   // quad_perm xor1
            DPP_ADD(v, 0x4E);   // quad_perm xor2
            DPP_ADD(v, 0x128);  // row_ror:8
            DPP_ADD(v, 0x124);  // row_ror:4  -> each lane = its 16-row sum
            const float sum = (rl(v, 0) + rl(v, 16)) + (rl(v, 32) + rl(v, 48));

            const float g = fmaf(w, __builtin_amdgcn_rcpf(sum), DETC);
            __builtin_nontemporal_store(g, gamma_out + (size_t)i * K + lane); // coalesced 256B

            accN += g;
            accS  = fmaf(g, u_s, accS);
#pragma unroll
            for (int d = 0; d < P; ++d) accM[d] = fmaf(g, row[d], accM[d]);
        }
    }

    // ---- block combine in LDS, then one set of striped global atomics ----
    __shared__ float red[WS_FLOATS];   // [0,K) N | [K,2K) S | [2K,..) M[d][k]
    for (int idx = threadIdx.x; idx < WS_FLOATS; idx += NTHREADS) red[idx] = 0.f;
    __syncthreads();

    atomicAdd(&red[lane], accN);
    atomicAdd(&red[K + lane], accS);
#pragma unroll
    for (int d = 0; d < P; ++d) atomicAdd(&red[2 * K + d * K + lane], accM[d]);
    __syncthreads();

    // stripe the cross-block combine over NCOPIES accumulator copies:
    // contention per address drops NBLOCKS -> NBLOCKS/NCOPIES (= 64)
    float* wsc = ws + (size_t)(blockIdx.x & (NCOPIES - 1)) * WS_FLOATS;
    for (int idx = threadIdx.x; idx < WS_FLOATS; idx += NTHREADS)
        atomicAdd(&wsc[idx], red[idx]);
    __syncthreads();   // all this block's global atomics drained (vmcnt(0))

    // ---- decoupled finalize: last block reduces the copies + small outputs ----
    __shared__ int lastf;
    if (threadIdx.x == 0) {
        __threadfence();
        const int c = atomicAdd((int*)(ws + (size_t)NCOPIES * WS_FLOATS), 1);
        lastf = (c == NBLOCKS - 1);
    }
    __syncthreads();
    if (lastf) {
        __threadfence();
        // cooperative, coalesced reduction of the 32 copies into LDS
        for (int idx = threadIdx.x; idx < WS_FLOATS; idx += NTHREADS) {
            float s = 0.f;
#pragma unroll 4
            for (int c = 0; c < NCOPIES; ++c)
                s += __hip_atomic_load(&ws[(size_t)c * WS_FLOATS + idx],
                                       __ATOMIC_RELAXED, __HIP_MEMORY_SCOPE_AGENT);
            red[idx] = s;
        }
        __syncthreads();

        const int k = threadIdx.x;
        if (k < K) {
            const float Nk = red[k];
            const float S  = red[K + k];
            float* pi_new      = out_tail;
            float* mu_new      = out_tail + K;
            float* log_cov_new = out_tail + K + K * P;

            pi_new[k] = Nk / (float)NPTS;
            const float invN = 1.f / Nk;
            float m2 = 0.f;
#pragma unroll
            for (int d = 0; d < P; ++d) {
                const float md = red[2 * K + d * K + k] * invN;
                mu_new[k * P + d] = md;
                m2 = fmaf(md, md, m2);
            }
            const float cov = (S - Nk * m2) / (32.f * Nk);
            log_cov_new[k] = logf(cov);
        }
    }
}

extern "C" void kernel_launch(void* const* d_in, const int* in_sizes, int n_in,
                              void* d_out, int out_size, void* d_ws, size_t ws_size,
                              hipStream_t stream)
{
    const float* mu_phi      = (const float*)d_in[0];
    const float* log_cov_phi = (const float*)d_in[1];
    const float* pi_k        = (const float*)d_in[2];
    const float* mu_k        = (const float*)d_in[3];
    const float* log_cov_k   = (const float*)d_in[4];
    float* out = (float*)d_out;
    float* ws  = (float*)d_ws;

    hipMemsetAsync(ws, 0, ((size_t)NCOPIES * WS_FLOATS + 1) * sizeof(float), stream);
    em_pass<<<NBLOCKS, NTHREADS, 0, stream>>>(mu_phi, log_cov_phi, pi_k, mu_k,
                                              log_cov_k, out,
                                              out + (size_t)NPTS * K, ws);
}